// Round 3
// baseline (378.798 us; speedup 1.0000x reference)
//
#include <hip/hip_runtime.h>
#include <hip/hip_bf16.h>

// ---------------------------------------------------------------------------
// TinyMNISTNet: out = relu(x @ Wq1^T + b1) @ Wq2^T + b2, ternarized weights.
// x: [65536,784] fp32; W1: [64,784]; b1:[64]; W2:[10,64]; b2:[10]; out fp32 [65536,10].
//
// R3: (a) ONE ternarize kernel (redundant per-block delta, per-block f64
//     partials, no atomics, no memset); (b) fused K-loop fully unrolled with
//     depth-3 register pipeline and branchless tail (clamped reload x zero
//     weights); alphas reduced in the fused epilogue via f64 shuffle butterfly.
// ---------------------------------------------------------------------------

typedef __attribute__((ext_vector_type(4))) float f32x4;
typedef __attribute__((ext_vector_type(8))) short s16x8;
typedef __attribute__((ext_vector_type(4))) short s16x4;

#define K1 784
#define K1_PAD 800          // 25 K-steps of 32
#define NHID 64
#define NOUT 10

// round-to-nearest-even f32 -> bf16 bits (finite inputs)
static __device__ __forceinline__ unsigned short f2bf_rne(float f) {
    unsigned int u = __builtin_bit_cast(unsigned int, f);
    unsigned int r = u + 0x7FFFu + ((u >> 16) & 1u);
    return (unsigned short)(r >> 16);
}

// block-wide f64 sum for 256-thread blocks (4 waves); all threads get result
static __device__ double block_sum256(double v, double* red) {
    #pragma unroll
    for (int off = 32; off > 0; off >>= 1) v += __shfl_down(v, off, 64);
    const int w = threadIdx.x >> 6;
    const int lane = threadIdx.x & 63;
    __syncthreads();                 // protect red[] reuse across calls
    if (lane == 0) red[w] = v;
    __syncthreads();
    return red[0] + red[1] + red[2] + red[3];
}

// ---------------------------------------------------------------------------
// parts layout (doubles): [0..63] sm1 partials, [64..127] cn1 partials,
//                         [128] alpha2
// Grid: exactly 64 blocks x 256. Block b: full redundant sum|W1| -> delta1
// (identical across blocks), quantize W1 row b, write (sm,cn) partial.
// Block 0 additionally does W2 end-to-end.
// ---------------------------------------------------------------------------
__global__ __launch_bounds__(256) void tern_kernel(
    const float* __restrict__ W1, const float* __restrict__ W2,
    unsigned short* __restrict__ W1q, unsigned short* __restrict__ W2q,
    double* __restrict__ parts)
{
    __shared__ double red[4];
    const int tid = threadIdx.x;

    // full redundant sum of |W1| (64 x 200KB from L2 — trivial, no sync needed)
    double s = 0.0;
    for (int i = tid; i < NHID * K1; i += 256) s += (double)fabsf(W1[i]);
    s = block_sum256(s, red);
    const float delta1 = (float)(0.7 * (s / (double)(NHID * K1)));

    // quantize row n = blockIdx.x into padded [64][800] bf16 signs
    const int n = blockIdx.x;
    double sm = 0.0, cn = 0.0;
    for (int k = tid; k < K1_PAD; k += 256) {
        unsigned short v = 0;
        if (k < K1) {
            float w = W1[n * K1 + k];
            float a = fabsf(w);
            if (a > delta1) { v = (w > 0.0f) ? 0x3F80u : 0xBF80u; sm += (double)a; cn += 1.0; }
        }
        W1q[n * K1_PAD + k] = v;
    }
    sm = block_sum256(sm, red);
    cn = block_sum256(cn, red);
    if (tid == 0) { parts[n] = sm; parts[64 + n] = cn; }

    if (blockIdx.x == 0) {
        double s2 = 0.0;
        for (int i = tid; i < NOUT * NHID; i += 256) s2 += (double)fabsf(W2[i]);
        s2 = block_sum256(s2, red);
        const float delta2 = (float)(0.7 * (s2 / (double)(NOUT * NHID)));
        double sm2 = 0.0, cn2 = 0.0;
        for (int i = tid; i < 16 * NHID; i += 256) {
            int r = i >> 6, k = i & 63;
            unsigned short v = 0;
            if (r < NOUT) {
                float w = W2[r * NHID + k];
                float a = fabsf(w);
                if (a > delta2) { v = (w > 0.0f) ? 0x3F80u : 0xBF80u; sm2 += (double)a; cn2 += 1.0; }
            }
            W2q[i] = v;
        }
        sm2 = block_sum256(sm2, red);
        cn2 = block_sum256(cn2, red);
        if (tid == 0) parts[128] = sm2 / fmax(cn2, 1.0);
    }
}

// ---------------------------------------------------------------------------
// Fused 2-layer kernel. 256 threads = 4 waves; each wave: 16 batch rows x all
// 64 hidden features, then 16x10 outputs. Grid: nrows/64 = 1024 (4 blocks/CU).
//
// K-loop: 25 chunks of 32 floats/row, fully unrolled, depth-3 register
// pipeline (6 dwordx4 in flight/wave). Staging roles: 8 lanes/row x 16B
// (contiguous 128B per row -> fully coalesced). Tail chunk 24 is branchless:
// lanes scol>=4 reload in-row floats (scol&3) whose k-positions >=784 carry
// zero weights, contributing exactly 0.
//
// MFMA 16x16x32 bf16 layouts (m89/m91/m120-verified):
//   A[m=lane&15][k=quad*8+j], B[n=lane&15][k=quad*8+j], C/D: col=lane&15, row=quad*4+reg
// ---------------------------------------------------------------------------
__global__ __launch_bounds__(256) void fused_kernel(
    const float* __restrict__ x,
    const float* __restrict__ b1,
    const float* __restrict__ b2,
    const short* __restrict__ W1q,   // [64][800] bf16 signs
    const short* __restrict__ W2q,   // [16][64]  bf16 signs
    const double* __restrict__ parts,
    float* __restrict__ out)
{
    const int tid  = threadIdx.x;
    const int wave = tid >> 6;
    const int lane = tid & 63;
    const int low  = lane & 15;
    const int quad = lane >> 4;
    const int m0 = blockIdx.x * 64 + wave * 16;

    const int srow = lane >> 3;      // 0..7
    const int scol = lane & 7;       // *16B
    const float* g0 = x + (size_t)(m0 + srow) * K1 + scol * 4;
    const float* g1 = g0 + 8 * K1;
    // tail chunk base: float 768 + clamped lane column (always in-row)
    const float* g0t = x + (size_t)(m0 + srow) * K1 + 768 + (scol & 3) * 4;
    const float* g1t = g0t + 8 * K1;

    // B base pointers: immediate offsets ks*64B (<=1536) fit the 13-bit imm
    const short* wb0 = W1q + (size_t)(low     ) * K1_PAD + quad * 8;
    const short* wb1 = W1q + (size_t)(low + 16) * K1_PAD + quad * 8;
    const short* wb2 = W1q + (size_t)(low + 32) * K1_PAD + quad * 8;
    const short* wb3 = W1q + (size_t)(low + 48) * K1_PAD + quad * 8;

    __shared__ __align__(16) unsigned short stage[4][2][16][32];  // wave-private dbuf
    __shared__ __align__(16) unsigned short h_lds[4][16][72];     // layer-2 A staging

    f32x4 acc[4];
    #pragma unroll
    for (int nt = 0; nt < 4; ++nt) acc[nt] = (f32x4){0.f, 0.f, 0.f, 0.f};

    // prologue: 3 chunks in flight
    f32x4 q0[3], q1[3];
    q0[0] = *(const f32x4*)(g0);       q1[0] = *(const f32x4*)(g1);
    q0[1] = *(const f32x4*)(g0 + 32);  q1[1] = *(const f32x4*)(g1 + 32);
    q0[2] = *(const f32x4*)(g0 + 64);  q1[2] = *(const f32x4*)(g1 + 64);

    #pragma unroll
    for (int ks = 0; ks < 25; ++ks) {
        const int slot = ks % 3;
        const int buf  = ks & 1;
        f32x4 c0 = q0[slot], c1 = q1[slot];

        // refill slot with chunk ks+3 (depth-3 pipeline)
        if (ks + 3 < 24) {
            q0[slot] = *(const f32x4*)(g0 + (ks + 3) * 32);
            q1[slot] = *(const f32x4*)(g1 + (ks + 3) * 32);
        } else if (ks + 3 == 24) {
            q0[slot] = *(const f32x4*)(g0t);
            q1[slot] = *(const f32x4*)(g1t);
        }

        // convert current chunk -> bf16, stash to wave-private LDS
        s16x4 p0, p1;
        p0[0] = (short)f2bf_rne(c0[0]); p0[1] = (short)f2bf_rne(c0[1]);
        p0[2] = (short)f2bf_rne(c0[2]); p0[3] = (short)f2bf_rne(c0[3]);
        p1[0] = (short)f2bf_rne(c1[0]); p1[1] = (short)f2bf_rne(c1[1]);
        p1[2] = (short)f2bf_rne(c1[2]); p1[3] = (short)f2bf_rne(c1[3]);
        *(s16x4*)&stage[wave][buf][srow][scol * 4]     = p0;
        *(s16x4*)&stage[wave][buf][8 + srow][scol * 4] = p1;

        // wave-private LDS write -> cross-lane read: drain DS pipe
        __asm__ volatile("s_waitcnt lgkmcnt(0)" ::: "memory");

        s16x8 a = *(const s16x8*)&stage[wave][buf][low][quad * 8];
        s16x8 bf0 = *(const s16x8*)(wb0 + ks * 32);
        s16x8 bf1 = *(const s16x8*)(wb1 + ks * 32);
        s16x8 bf2 = *(const s16x8*)(wb2 + ks * 32);
        s16x8 bf3 = *(const s16x8*)(wb3 + ks * 32);
        acc[0] = __builtin_amdgcn_mfma_f32_16x16x32_bf16(a, bf0, acc[0], 0, 0, 0);
        acc[1] = __builtin_amdgcn_mfma_f32_16x16x32_bf16(a, bf1, acc[1], 0, 0, 0);
        acc[2] = __builtin_amdgcn_mfma_f32_16x16x32_bf16(a, bf2, acc[2], 0, 0, 0);
        acc[3] = __builtin_amdgcn_mfma_f32_16x16x32_bf16(a, bf3, acc[3], 0, 0, 0);
    }

    // ---- alphas: reduce 64 f64 partials with a shuffle butterfly ----
    double smd = parts[lane];
    double cnd = parts[64 + lane];
    #pragma unroll
    for (int off = 32; off > 0; off >>= 1) {
        smd += __shfl_down(smd, off, 64);
        cnd += __shfl_down(cnd, off, 64);
    }
    smd = __shfl(smd, 0, 64);
    cnd = __shfl(cnd, 0, 64);
    const float alpha1 = (float)(smd / fmax(cnd, 1.0));
    const float alpha2 = (float)parts[128];

    // ---- epilogue 1: alpha1*acc + b1, relu, bf16 -> LDS (C-layout -> A-layout) ----
    #pragma unroll
    for (int nt = 0; nt < 4; ++nt) {
        const int n = nt * 16 + low;
        const float bias = b1[n];
        #pragma unroll
        for (int r = 0; r < 4; ++r) {
            float hv = fmaxf(0.0f, fmaf(alpha1, acc[nt][r], bias));
            h_lds[wave][quad * 4 + r][n] = f2bf_rne(hv);
        }
    }
    __asm__ volatile("s_waitcnt lgkmcnt(0)" ::: "memory");

    // ---- layer 2: [16x64] x [64x16] via 2 MFMA steps ----
    s16x8 a0 = *(const s16x8*)(&h_lds[wave][low][quad * 8]);
    s16x8 a1 = *(const s16x8*)(&h_lds[wave][low][32 + quad * 8]);
    s16x8 w0 = *(const s16x8*)(W2q + low * 64 + quad * 8);
    s16x8 w1 = *(const s16x8*)(W2q + low * 64 + 32 + quad * 8);

    f32x4 acc2 = (f32x4){0.f, 0.f, 0.f, 0.f};
    acc2 = __builtin_amdgcn_mfma_f32_16x16x32_bf16(a0, w0, acc2, 0, 0, 0);
    acc2 = __builtin_amdgcn_mfma_f32_16x16x32_bf16(a1, w1, acc2, 0, 0, 0);

    // ---- epilogue 2: alpha2*acc2 + b2, store fp32 ----
    if (low < NOUT) {
        const float bias2 = b2[low];
        #pragma unroll
        for (int r = 0; r < 4; ++r) {
            const int row = m0 + quad * 4 + r;
            out[(size_t)row * NOUT + low] = fmaf(alpha2, acc2[r], bias2);
        }
    }
}

// ---------------------------------------------------------------------------
extern "C" void kernel_launch(void* const* d_in, const int* in_sizes, int n_in,
                              void* d_out, int out_size, void* d_ws, size_t ws_size,
                              hipStream_t stream) {
    const float* x  = (const float*)d_in[0];
    const float* W1 = (const float*)d_in[1];
    const float* b1 = (const float*)d_in[2];
    const float* W2 = (const float*)d_in[3];
    const float* b2 = (const float*)d_in[4];
    float* out = (float*)d_out;

    const int nrows = in_sizes[0] / K1;   // 65536

    // ws layout: parts 129 doubles (pad to 2KB) | W1q [64*800] bf16 | W2q [16*64] bf16
    double* parts = (double*)d_ws;
    unsigned short* W1q = (unsigned short*)((char*)d_ws + 2048);
    unsigned short* W2q = W1q + NHID * K1_PAD;

    tern_kernel<<<64, 256, 0, stream>>>(W1, W2, W1q, W2q, parts);

    const int nblocks = nrows / 64;       // 64 rows per block (16 per wave)
    fused_kernel<<<nblocks, 256, 0, stream>>>(x, b1, b2, (const short*)W1q,
                                              (const short*)W2q, parts, out);
}

// Round 5
// 378.280 us; speedup vs baseline: 1.0014x; 1.0014x over previous
//
#include <hip/hip_runtime.h>
#include <hip/hip_bf16.h>

// ---------------------------------------------------------------------------
// TinyMNISTNet: out = relu(x @ Wq1^T + b1) @ Wq2^T + b2, ternarized weights.
// x: [65536,784] fp32; W1: [64,784]; b1:[64]; W2:[10,64]; b2:[10]; out fp32 [65536,10].
//
// R5 = R4 with the compile fix (__builtin_memcpy pun instead of
// __builtin_bit_cast on __hip_bfloat162):
//   - R2's measured-best ROLLED K-loop (R3 full unroll regressed)
//   - packed bf16 converts (v_cvt_pk_bf16_f32) instead of scalar RNE emu
//   - B-fragment loads hoisted ABOVE the LDS drain; drain is
//     s_waitcnt(lgkmcnt(0)) builtin, not an asm memory-clobber
//   - single ternarize kernel (no atomics/memset), alpha1 reduced by a
//     f64 shuffle butterfly in the fused epilogue
// ---------------------------------------------------------------------------

typedef __attribute__((ext_vector_type(4))) float f32x4;
typedef __attribute__((ext_vector_type(8))) short s16x8;
typedef __attribute__((ext_vector_type(4))) short s16x4;

#define K1 784
#define K1_PAD 800          // 25 K-steps of 32
#define NHID 64
#define NOUT 10

// lgkmcnt(0), vmcnt=63, expcnt=7  (gfx9 encoding)
#define WAIT_LGKM0() __builtin_amdgcn_s_waitcnt(0xC07F)

// packed f32x2 -> bf16x2 (RNE, v_cvt_pk_bf16_f32 on gfx950); inputs finite
static __device__ __forceinline__ unsigned int cvt_pk_bf16(float a, float b) {
    float2 f; f.x = a; f.y = b;
    __hip_bfloat162 h = __float22bfloat162_rn(f);
    unsigned int u;
    __builtin_memcpy(&u, &h, 4);      // .x low 16, .y high 16
    return u;
}

// scalar RNE f32->bf16 bits (epilogue only)
static __device__ __forceinline__ unsigned short f2bf_rne(float f) {
    unsigned int u = __builtin_bit_cast(unsigned int, f);
    unsigned int r = u + 0x7FFFu + ((u >> 16) & 1u);
    return (unsigned short)(r >> 16);
}

// block-wide f64 sum for 256-thread blocks (4 waves); all threads get result
static __device__ double block_sum256(double v, double* red) {
    #pragma unroll
    for (int off = 32; off > 0; off >>= 1) v += __shfl_down(v, off, 64);
    const int w = threadIdx.x >> 6;
    const int lane = threadIdx.x & 63;
    __syncthreads();                 // protect red[] reuse across calls
    if (lane == 0) red[w] = v;
    __syncthreads();
    return red[0] + red[1] + red[2] + red[3];
}

// ---------------------------------------------------------------------------
// parts (doubles): [0..63] sm1 partials, [64..127] cn1 partials, [128] alpha2
// Grid: 64 blocks x 256. Each block: redundant full sum|W1| (identical delta1
// in every block), quantize W1 row b, write (sm,cn) partial. Block 0 also
// does W2 end-to-end and stores alpha2.
// ---------------------------------------------------------------------------
__global__ __launch_bounds__(256) void tern_kernel(
    const float* __restrict__ W1, const float* __restrict__ W2,
    unsigned short* __restrict__ W1q, unsigned short* __restrict__ W2q,
    double* __restrict__ parts)
{
    __shared__ double red[4];
    const int tid = threadIdx.x;

    double s = 0.0;
    for (int i = tid; i < NHID * K1; i += 256) s += (double)fabsf(W1[i]);
    s = block_sum256(s, red);
    const float delta1 = (float)(0.7 * (s / (double)(NHID * K1)));

    const int n = blockIdx.x;
    double sm = 0.0, cn = 0.0;
    for (int k = tid; k < K1_PAD; k += 256) {
        unsigned short v = 0;
        if (k < K1) {
            float w = W1[n * K1 + k];
            float a = fabsf(w);
            if (a > delta1) { v = (w > 0.0f) ? 0x3F80u : 0xBF80u; sm += (double)a; cn += 1.0; }
        }
        W1q[n * K1_PAD + k] = v;
    }
    sm = block_sum256(sm, red);
    cn = block_sum256(cn, red);
    if (tid == 0) { parts[n] = sm; parts[64 + n] = cn; }

    if (blockIdx.x == 0) {
        double s2 = 0.0;
        for (int i = tid; i < NOUT * NHID; i += 256) s2 += (double)fabsf(W2[i]);
        s2 = block_sum256(s2, red);
        const float delta2 = (float)(0.7 * (s2 / (double)(NOUT * NHID)));
        double sm2 = 0.0, cn2 = 0.0;
        for (int i = tid; i < 16 * NHID; i += 256) {
            int r = i >> 6, k = i & 63;
            unsigned short v = 0;
            if (r < NOUT) {
                float w = W2[r * NHID + k];
                float a = fabsf(w);
                if (a > delta2) { v = (w > 0.0f) ? 0x3F80u : 0xBF80u; sm2 += (double)a; cn2 += 1.0; }
            }
            W2q[i] = v;
        }
        sm2 = block_sum256(sm2, red);
        cn2 = block_sum256(cn2, red);
        if (tid == 0) parts[128] = sm2 / fmax(cn2, 1.0);
    }
}

// ---------------------------------------------------------------------------
// Fused 2-layer kernel. 256 threads = 4 waves; each wave: 16 batch rows x all
// 64 hidden features, then 16x10 outputs. Grid: nrows/64 = 1024 (4 blocks/CU).
//
// Rolled K-loop (R2 structure): depth-1 register prefetch of the next 16x32
// x-chunk (coalesced 128B/row), packed bf16 convert, wave-private LDS stage
// (write b64 / drain lgkmcnt(0) only / read b128), B-loads hoisted above the
// drain so they stay in flight, 4 MFMA.
//
// MFMA 16x16x32 bf16 layouts (m89/m91/m120-verified):
//   A[m=lane&15][k=quad*8+j], B[n=lane&15][k=quad*8+j], C/D: col=lane&15, row=quad*4+reg
// ---------------------------------------------------------------------------
__global__ __launch_bounds__(256) void fused_kernel(
    const float* __restrict__ x,
    const float* __restrict__ b1,
    const float* __restrict__ b2,
    const short* __restrict__ W1q,   // [64][800] bf16 signs
    const short* __restrict__ W2q,   // [16][64]  bf16 signs
    const double* __restrict__ parts,
    float* __restrict__ out)
{
    const int tid  = threadIdx.x;
    const int wave = tid >> 6;
    const int lane = tid & 63;
    const int low  = lane & 15;
    const int quad = lane >> 4;
    const int m0 = blockIdx.x * 64 + wave * 16;

    // staging-load role: 8 lanes per row, 16B per lane (contiguous 128B/row)
    const int srow = lane >> 3;      // 0..7
    const int scol = lane & 7;       // *16B
    const float* g0 = x + (size_t)(m0 + srow) * K1 + scol * 4;
    const float* g1 = g0 + 8 * K1;

    const short* wb0 = W1q + (size_t)(low     ) * K1_PAD + quad * 8;
    const short* wb1 = W1q + (size_t)(low + 16) * K1_PAD + quad * 8;
    const short* wb2 = W1q + (size_t)(low + 32) * K1_PAD + quad * 8;
    const short* wb3 = W1q + (size_t)(low + 48) * K1_PAD + quad * 8;

    __shared__ __align__(16) unsigned short stage[4][2][16][32];  // wave-private dbuf
    __shared__ __align__(16) unsigned short h_lds[4][16][72];     // layer-2 A staging

    f32x4 acc[4];
    #pragma unroll
    for (int nt = 0; nt < 4; ++nt) acc[nt] = (f32x4){0.f, 0.f, 0.f, 0.f};

    const f32x4 zero4 = (f32x4){0.f, 0.f, 0.f, 0.f};

    // prologue: chunk 0 in flight
    f32x4 c0 = *(const f32x4*)(g0);
    f32x4 c1 = *(const f32x4*)(g1);

    int buf = 0;
    for (int ks = 0; ks < 25; ++ks) {
        // depth-1 prefetch of next chunk
        f32x4 n0 = zero4, n1 = zero4;
        if (ks < 24) {
            const int kf = (ks + 1) * 32 + scol * 4;
            if (kf < K1) {               // tail chunk 24: only scol<4 valid
                n0 = *(const f32x4*)(g0 + (ks + 1) * 32);
                n1 = *(const f32x4*)(g1 + (ks + 1) * 32);
            }
        }

        // B-fragment loads issued BEFORE the LDS drain (stay in flight)
        s16x8 bf0 = *(const s16x8*)(wb0 + ks * 32);
        s16x8 bf1 = *(const s16x8*)(wb1 + ks * 32);
        s16x8 bf2 = *(const s16x8*)(wb2 + ks * 32);
        s16x8 bf3 = *(const s16x8*)(wb3 + ks * 32);

        // packed convert current chunk -> bf16, stash to wave-private LDS
        unsigned int pk[4];
        pk[0] = cvt_pk_bf16(c0[0], c0[1]); pk[1] = cvt_pk_bf16(c0[2], c0[3]);
        pk[2] = cvt_pk_bf16(c1[0], c1[1]); pk[3] = cvt_pk_bf16(c1[2], c1[3]);
        s16x4 p0, p1;
        __builtin_memcpy(&p0, &pk[0], 8);
        __builtin_memcpy(&p1, &pk[2], 8);
        *(s16x4*)&stage[wave][buf][srow][scol * 4]     = p0;
        *(s16x4*)&stage[wave][buf][8 + srow][scol * 4] = p1;

        WAIT_LGKM0();   // wave-private LDS write -> cross-lane read (DS drain only)

        s16x8 a = *(const s16x8*)&stage[wave][buf][low][quad * 8];
        acc[0] = __builtin_amdgcn_mfma_f32_16x16x32_bf16(a, bf0, acc[0], 0, 0, 0);
        acc[1] = __builtin_amdgcn_mfma_f32_16x16x32_bf16(a, bf1, acc[1], 0, 0, 0);
        acc[2] = __builtin_amdgcn_mfma_f32_16x16x32_bf16(a, bf2, acc[2], 0, 0, 0);
        acc[3] = __builtin_amdgcn_mfma_f32_16x16x32_bf16(a, bf3, acc[3], 0, 0, 0);

        c0 = n0; c1 = n1; buf ^= 1;
    }

    // ---- alpha1 from 64 f64 partials via shuffle butterfly; alpha2 direct ----
    double smd = parts[lane];
    double cnd = parts[64 + lane];
    #pragma unroll
    for (int off = 32; off > 0; off >>= 1) {
        smd += __shfl_down(smd, off, 64);
        cnd += __shfl_down(cnd, off, 64);
    }
    smd = __shfl(smd, 0, 64);
    cnd = __shfl(cnd, 0, 64);
    const float alpha1 = (float)(smd / fmax(cnd, 1.0));
    const float alpha2 = (float)parts[128];

    // ---- epilogue 1: alpha1*acc + b1, relu, bf16 -> LDS (C-layout -> A-layout) ----
    #pragma unroll
    for (int nt = 0; nt < 4; ++nt) {
        const int n = nt * 16 + low;
        const float bias = b1[n];
        #pragma unroll
        for (int r = 0; r < 4; ++r) {
            float hv = fmaxf(0.0f, fmaf(alpha1, acc[nt][r], bias));
            h_lds[wave][quad * 4 + r][n] = f2bf_rne(hv);
        }
    }
    WAIT_LGKM0();

    // ---- layer 2: [16x64] x [64x16] via 2 MFMA steps ----
    s16x8 a0 = *(const s16x8*)(&h_lds[wave][low][quad * 8]);
    s16x8 a1 = *(const s16x8*)(&h_lds[wave][low][32 + quad * 8]);
    s16x8 w0 = *(const s16x8*)(W2q + low * 64 + quad * 8);
    s16x8 w1 = *(const s16x8*)(W2q + low * 64 + 32 + quad * 8);

    f32x4 acc2 = (f32x4){0.f, 0.f, 0.f, 0.f};
    acc2 = __builtin_amdgcn_mfma_f32_16x16x32_bf16(a0, w0, acc2, 0, 0, 0);
    acc2 = __builtin_amdgcn_mfma_f32_16x16x32_bf16(a1, w1, acc2, 0, 0, 0);

    // ---- epilogue 2: alpha2*acc2 + b2, store fp32 ----
    if (low < NOUT) {
        const float bias2 = b2[low];
        #pragma unroll
        for (int r = 0; r < 4; ++r) {
            const int row = m0 + quad * 4 + r;
            out[(size_t)row * NOUT + low] = fmaf(alpha2, acc2[r], bias2);
        }
    }
}

// ---------------------------------------------------------------------------
extern "C" void kernel_launch(void* const* d_in, const int* in_sizes, int n_in,
                              void* d_out, int out_size, void* d_ws, size_t ws_size,
                              hipStream_t stream) {
    const float* x  = (const float*)d_in[0];
    const float* W1 = (const float*)d_in[1];
    const float* b1 = (const float*)d_in[2];
    const float* W2 = (const float*)d_in[3];
    const float* b2 = (const float*)d_in[4];
    float* out = (float*)d_out;

    const int nrows = in_sizes[0] / K1;   // 65536

    // ws layout: parts 129 doubles (pad to 2KB) | W1q [64*800] bf16 | W2q [16*64] bf16
    double* parts = (double*)d_ws;
    unsigned short* W1q = (unsigned short*)((char*)d_ws + 2048);
    unsigned short* W2q = W1q + NHID * K1_PAD;

    tern_kernel<<<64, 256, 0, stream>>>(W1, W2, W1q, W2q, parts);

    const int nblocks = nrows / 64;       // 64 rows per block (16 per wave)
    fused_kernel<<<nblocks, 256, 0, stream>>>(x, b1, b2, (const short*)W1q,
                                              (const short*)W2q, parts, out);
}